// Round 8
// baseline (159.362 us; speedup 1.0000x reference)
//
#include <hip/hip_runtime.h>

// VectorQuantizer: B=16, D=64, H=64, W=64, K=1024
#define DD 64
#define KK 1024
#define NPTS 65536
#define TOTAL 4194304
#define NBLK_TOTAL 1024   // A(512) + B(512) ticket target

// Output layout (flat f32): quantized[4194304], L1, L2, idx[65536]
#define OFF_L1 4194304
#define OFF_L2 4194305
#define OFF_IDX 4194306

// ws layout (bytes): [0] f32 sum, [8] u32 ticket, enh @ float 64 (byte 256),
// ehT @ byte 65536 (128KB), elT @ byte 196608 (128KB). (<=328KB used)
#define WS_ENH_F 64
#define WS_EHT_BYTE 65536
#define WS_ELT_BYTE (65536 + 131072)

// score = dot(x,e) + 512 - ||e||^2/2  (argmax == argmin distance; +512 keeps
// all scores positive so float bits are monotone -> packed uint compare).
// Rescue margin: 32-ulp granule (<=2e-3) + bf16x3 err (~6e-4) + slack.
#define MARGIN_S 0.006f

typedef __attribute__((ext_vector_type(8))) short short8;
typedef __attribute__((ext_vector_type(4))) float f32x4;

__device__ __forceinline__ unsigned short bf16_rne(float f) {
    unsigned b = __float_as_uint(f);
    return (unsigned short)((b + 0x7FFFu + ((b >> 16) & 1u)) >> 16);
}
__device__ __forceinline__ float bf16_to_f(unsigned short h) {
    return __uint_as_float(((unsigned)h) << 16);
}
__device__ __forceinline__ unsigned umax(unsigned a, unsigned b) { return a > b ? a : b; }
__device__ __forceinline__ unsigned umin(unsigned a, unsigned b) { return a < b ? a : b; }
// async global->LDS DMA, 16B per lane; LDS dest = wave-uniform base + lane*16
__device__ __forceinline__ void gld_lds16(const void* g, void* l) {
    __builtin_amdgcn_global_load_lds(
        (const __attribute__((address_space(1))) void*)g,
        (__attribute__((address_space(3))) void*)l, 16, 0, 0);
}
// swizzled position of element d within a 64-elem row r (16B-granule XOR key)
__device__ __forceinline__ int swz(int r, int d) {
    return ((d & ~7) ^ ((r & 7) << 3)) | (d & 7);
}

// ---------- kernel 1: enh + swizzled bf16 hi/lo codebook [k][64] ----------
__global__ __launch_bounds__(256) void prep_kernel(const float* __restrict__ e,
                                                   float* __restrict__ enh,
                                                   unsigned short* __restrict__ ehT,
                                                   unsigned short* __restrict__ elT,
                                                   float* __restrict__ sum,
                                                   unsigned* __restrict__ tick) {
    __shared__ unsigned short tH[64 * 64];   // 8KB [code_local][swz d]
    __shared__ unsigned short tL[64 * 64];
    __shared__ float ps[4 * 64];
    const int tid = threadIdx.x, wave = tid >> 6, lane = tid & 63;
    if (blockIdx.x == 0 && tid == 0) { *sum = 0.f; *tick = 0u; }
    const int k = blockIdx.x * 64 + lane;    // this thread's code
    float s2 = 0.f;
    short8 hh[2], ll[2];
#pragma unroll
    for (int g = 0; g < 2; ++g)
#pragma unroll
        for (int j = 0; j < 8; ++j) {
            const int d = wave * 16 + g * 8 + j;
            const float v = e[d * KK + k];   // lanes k-contiguous -> 256B coalesced
            const unsigned short h = bf16_rne(v);
            hh[g][j] = (short)h;
            ll[g][j] = (short)bf16_rne(v - bf16_to_f(h));
            s2 = fmaf(v, v, s2);
        }
    ps[wave * 64 + lane] = s2;
#pragma unroll
    for (int g = 0; g < 2; ++g) {
        const int pos = lane * 64 + ((wave * 16 + g * 8) ^ ((k & 7) << 3));
        *(short8*)(tH + pos) = hh[g];
        *(short8*)(tL + pos) = ll[g];
    }
    __syncthreads();
    if (wave == 0) {
        const float t = ps[lane] + ps[64 + lane] + ps[128 + lane] + ps[192 + lane];
        enh[k] = 512.0f - 0.5f * t;
    }
    {
        const short8* srcH = (const short8*)tH;
        const short8* srcL = (const short8*)tL;
        short8* dstH = (short8*)(ehT + blockIdx.x * 64 * 64);
        short8* dstL = (short8*)(elT + blockIdx.x * 64 * 64);
        dstH[tid * 2]     = srcH[tid * 2];
        dstH[tid * 2 + 1] = srcH[tid * 2 + 1];
        dstL[tid * 2]     = srcL[tid * 2];
        dstL[tid * 2 + 1] = srcL[tid * 2 + 1];
    }
}

// ======================= WITHIN-RUN A/B EXPERIMENT =======================
// Cross-container variance measured ~1.5x (r0 body: 58.5us on r0's container,
// 87us bit-identical on r7's). All cross-run deltas since r1 are suspect.
// This round: A = r0 body (control) on blocks 0-511; B = counted-vmcnt
// triple-buffer (T3/T4, no sched_barrier) on blocks 512-1023. Same container,
// back-to-back dispatches -> rocprof gives a clean structural comparison.

// ---------- kernel 2A: r0 body verbatim (control), first 512 blocks ----------
__global__ __launch_bounds__(256) void vq_gemm_a(const float* __restrict__ x,
                                                 const float* __restrict__ e,
                                                 const float* __restrict__ enh,
                                                 const unsigned short* __restrict__ ehT,
                                                 const unsigned short* __restrict__ elT,
                                                 float* __restrict__ out,
                                                 float* __restrict__ sum,
                                                 unsigned* __restrict__ tick) {
    __shared__ __align__(16) char ebuf[2 * 16384];          // [buf][hi 8KB | lo 8KB]
    __shared__ __align__(16) unsigned short xbh[64 * 64];   // swizzled [p][d]
    __shared__ __align__(16) unsigned short xbl[64 * 64];
    __shared__ float mv1[64 * 2], mv2[64 * 2];
    __shared__ int mi1[64 * 2];
    __shared__ int ks[64];
    __shared__ float red[4];
    __shared__ float xp[64];
    __shared__ int rl[64];
    __shared__ int rn;
    __shared__ float rv[4];
    __shared__ int ri[4];

    const int tid = threadIdx.x;
    const int wave = tid >> 6, lane = tid & 63;
    const int n0 = blockIdx.x * 64;
    const int b = n0 >> 12;
    const int hw0 = n0 & 4095;

    const char* ehTb = (const char*)ehT;
    const char* elTb = (const char*)elT;
    const int lofs = wave * 1024 + lane * 16;

    {
        char* db = ebuf;
        gld_lds16(ehTb + lofs,        db + wave * 1024);
        gld_lds16(ehTb + 4096 + lofs, db + 4096 + wave * 1024);
        gld_lds16(elTb + lofs,        db + 8192 + wave * 1024);
        gld_lds16(elTb + 4096 + lofs, db + 12288 + wave * 1024);
    }
    if (tid == 0) rn = 0;

    float* xsc = (float*)(ebuf + 16384);
    {
        const int d = tid >> 2, ph = tid & 3;
        const float* src = x + ((b * DD + d) << 12) + hw0 + ph * 16;
        float* dst = xsc + d * 64 + ph * 16;
#pragma unroll
        for (int j = 0; j < 4; ++j)
            *(float4*)(dst + j * 4) = *(const float4*)(src + j * 4);
    }
    __syncthreads();
    {
        const int p = tid >> 2, dq = tid & 3;
#pragma unroll
        for (int s = 0; s < 16; ++s) {
            const int d = dq * 16 + s;
            const float f = xsc[d * 64 + p];
            const unsigned short h = bf16_rne(f);
            const int pos = p * 64 + swz(p, d);
            xbh[pos] = h;
            xbl[pos] = bf16_rne(f - bf16_to_f(h));
        }
    }
    __syncthreads();

    const int ln15 = lane & 15, q8 = (lane >> 4) * 8;
    const int wp = (wave >> 1) * 32;
    const int wc = (wave & 1) * 32;

    short8 ah[2][2], al[2][2];
#pragma unroll
    for (int rf = 0; rf < 2; ++rf)
#pragma unroll
        for (int kc = 0; kc < 2; ++kc) {
            const int pp = wp + rf * 16 + ln15;
            const int pos = pp * 64 + ((kc * 32 + q8) ^ ((pp & 7) << 3));
            ah[rf][kc] = *(const short8*)(xbh + pos);
            al[rf][kc] = *(const short8*)(xbl + pos);
        }

    unsigned v1u[8], v2u[8];
#pragma unroll
    for (int r = 0; r < 8; ++r) { v1u[r] = 0u; v2u[r] = 0u; }

    for (int kt = 0; kt < 16; ++kt) {
        __syncthreads();
        if (kt < 15) {
            const int nkt = kt + 1;
            char* db = ebuf + (nkt & 1) * 16384;
            const char* sH = ehTb + nkt * 8192 + lofs;
            const char* sL = elTb + nkt * 8192 + lofs;
            gld_lds16(sH,        db + wave * 1024);
            gld_lds16(sH + 4096, db + 4096 + wave * 1024);
            gld_lds16(sL,        db + 8192 + wave * 1024);
            gld_lds16(sL + 4096, db + 12288 + wave * 1024);
        }
        const unsigned short* ebH = (const unsigned short*)(ebuf + (kt & 1) * 16384);
        const unsigned short* ebL = ebH + 4096;

        f32x4 acc[2][2];
#pragma unroll
        for (int cf = 0; cf < 2; ++cf) {
            const float ec = enh[kt * 64 + wc + cf * 16 + ln15];
#pragma unroll
            for (int rf = 0; rf < 2; ++rf)
                acc[rf][cf] = (f32x4){ec, ec, ec, ec};
        }

#pragma unroll
        for (int kc = 0; kc < 2; ++kc) {
            short8 bh[2], bl[2];
#pragma unroll
            for (int cf = 0; cf < 2; ++cf) {
                const int c = wc + cf * 16 + ln15;
                const int pos = c * 64 + ((kc * 32 + q8) ^ ((c & 7) << 3));
                bh[cf] = *(const short8*)(ebH + pos);
                bl[cf] = *(const short8*)(ebL + pos);
            }
#pragma unroll
            for (int rf = 0; rf < 2; ++rf)
#pragma unroll
                for (int cf = 0; cf < 2; ++cf) {
                    acc[rf][cf] = __builtin_amdgcn_mfma_f32_16x16x32_bf16(al[rf][kc], bh[cf], acc[rf][cf], 0, 0, 0);
                    acc[rf][cf] = __builtin_amdgcn_mfma_f32_16x16x32_bf16(ah[rf][kc], bl[cf], acc[rf][cf], 0, 0, 0);
                    acc[rf][cf] = __builtin_amdgcn_mfma_f32_16x16x32_bf16(ah[rf][kc], bh[cf], acc[rf][cf], 0, 0, 0);
                }
        }

#pragma unroll
        for (int rf = 0; rf < 2; ++rf)
#pragma unroll
            for (int reg = 0; reg < 4; ++reg) {
                const int r = rf * 4 + reg;
                const unsigned k0 = (__float_as_uint(acc[rf][0][reg]) | 31u) ^ (unsigned)(kt * 2 + 0);
                const unsigned k1 = (__float_as_uint(acc[rf][1][reg]) | 31u) ^ (unsigned)(kt * 2 + 1);
                const unsigned a = umax(k0, k1), bb = umin(k0, k1);
                v2u[r] = umax(umax(v2u[r], umin(v1u[r], a)), bb);
                v1u[r] = umax(v1u[r], a);
            }
    }

#pragma unroll
    for (int r = 0; r < 8; ++r) {
        const unsigned c5 = 31u - (v1u[r] & 31u);
        int col = (int)(c5 >> 1) * 64 + wc + (int)(c5 & 1) * 16 + ln15;
        float val = __uint_as_float(v1u[r] & ~31u);
        float sec = __uint_as_float(v2u[r] & ~31u);
#pragma unroll
        for (int msk = 1; msk < 16; msk <<= 1) {
            const float ov = __shfl_xor(val, msk);
            const int oc = __shfl_xor(col, msk);
            const float os = __shfl_xor(sec, msk);
            sec = fmaxf(fmaxf(sec, os), fminf(val, ov));
            const bool t = (ov > val) || (ov == val && oc < col);
            val = t ? ov : val;
            col = t ? oc : col;
        }
        if (ln15 == 0) {
            const int q = lane >> 4;
            const int h = wave & 1;
            const int pt = wp + (r >> 2) * 16 + q * 4 + (r & 3);
            mv1[pt * 2 + h] = val;
            mi1[pt * 2 + h] = col;
            mv2[pt * 2 + h] = sec;
        }
    }
    __syncthreads();
    if (tid < 64) {
        const float va = mv1[tid * 2], vb = mv1[tid * 2 + 1];
        const int ia = mi1[tid * 2], ib = mi1[tid * 2 + 1];
        const bool t = (vb > va) || (vb == va && ib < ia);
        const float bv = t ? vb : va;
        const int bi = t ? ib : ia;
        const float sec = fmaxf(fmaxf(mv2[tid * 2], mv2[tid * 2 + 1]), fminf(va, vb));
        ks[tid] = bi;
        if (bv - sec < MARGIN_S) {
            const int w = atomicAdd(&rn, 1);
            rl[w] = tid;
        }
    }
    __syncthreads();

    const int lcnt = rn;
    for (int it = 0; it < lcnt; ++it) {
        const int pr = rl[it];
        if (tid < 64) xp[tid] = x[((b * DD + tid) << 12) + hw0 + pr];
        __syncthreads();
        float d0 = 0.f, d1 = 0.f, d2 = 0.f, d3 = 0.f;
#pragma unroll 8
        for (int dd = 0; dd < DD; ++dd) {
            const float xd = xp[dd];
            const float4 ev = *(const float4*)(e + dd * KK + tid * 4);
            d0 = fmaf(xd, ev.x, d0);
            d1 = fmaf(xd, ev.y, d1);
            d2 = fmaf(xd, ev.z, d2);
            d3 = fmaf(xd, ev.w, d3);
        }
        const float4 ea = *(const float4*)(enh + tid * 4);
        float bs = d0 + ea.x;
        int bi2 = tid * 4;
        if (d1 + ea.y > bs) { bs = d1 + ea.y; bi2 = tid * 4 + 1; }
        if (d2 + ea.z > bs) { bs = d2 + ea.z; bi2 = tid * 4 + 2; }
        if (d3 + ea.w > bs) { bs = d3 + ea.w; bi2 = tid * 4 + 3; }
#pragma unroll
        for (int m = 1; m < 64; m <<= 1) {
            const float ov = __shfl_xor(bs, m, 64);
            const int oi = __shfl_xor(bi2, m, 64);
            if (ov > bs || (ov == bs && oi < bi2)) { bs = ov; bi2 = oi; }
        }
        if (lane == 0) { rv[wave] = bs; ri[wave] = bi2; }
        __syncthreads();
        if (tid == 0) {
            float gs = rv[0];
            int gi = ri[0];
#pragma unroll
            for (int t2 = 1; t2 < 4; ++t2)
                if (rv[t2] > gs || (rv[t2] == gs && ri[t2] < gi)) { gs = rv[t2]; gi = ri[t2]; }
            ks[pr] = gi;
        }
        __syncthreads();
    }

    if (tid < 64) out[OFF_IDX + n0 + tid] = (float)ks[tid];

    const int p = tid & 63, dqr = tid >> 6;
    const int kp = ks[p];
    float lacc = 0.f;
#pragma unroll
    for (int s = 0; s < 16; ++s) {
        const int d = dqr * 16 + s;
        const float qv = e[d * KK + kp];
        const float xv = x[((b * DD + d) << 12) + hw0 + p];
        out[((b * DD + d) << 12) + hw0 + p] = qv;
        const float df = xv - qv;
        lacc = fmaf(df, df, lacc);
    }
#pragma unroll
    for (int off = 32; off > 0; off >>= 1) lacc += __shfl_down(lacc, off, 64);
    if (lane == 0) red[wave] = lacc;
    __syncthreads();
    if (tid == 0) {
        atomicAdd(sum, red[0] + red[1] + red[2] + red[3]);
        __threadfence();
        const unsigned old = atomicAdd(tick, 1u);
        if (old == (unsigned)(NBLK_TOTAL - 1)) {
            const float s = atomicAdd(sum, 0.0f);
            const float m = s * (1.0f / (float)TOTAL);
            out[OFF_L1] = m;
            out[OFF_L2] = m;
        }
    }
}

// ---------- kernel 2B: counted-vmcnt triple-buffer (T3/T4), blocks 512-1023 ----------
// Identical to A except: (1) 3x16KB tile buffers, DMA(kt+2) issued per iter,
// s_waitcnt vmcnt(8) [never 0 mid-loop] + raw s_barrier, NO sched_barrier;
// (2) enh staged to LDS so the loop has ZERO other vmcnt ops (the wait-count
// audit requires it): steady-state outstanding at the wait = DMA(kt)+DMA(kt+1)
// = 16 -> vmcnt(8) completes DMA(kt); kt=15 drains with vmcnt(0).
// Buffer safety: DMA(kt+2) targets buf[(kt-1)%3], whose readers all passed
// barrier(kt) (program order: compute(kt-1) precedes the wave's arrival).
__global__ __launch_bounds__(256) void vq_gemm_b(const float* __restrict__ x,
                                                 const float* __restrict__ e,
                                                 const float* __restrict__ enh,
                                                 const unsigned short* __restrict__ ehT,
                                                 const unsigned short* __restrict__ elT,
                                                 float* __restrict__ out,
                                                 float* __restrict__ sum,
                                                 unsigned* __restrict__ tick) {
    __shared__ __align__(16) char ebuf[3 * 16384];          // 48KB triple buffer
    __shared__ __align__(16) unsigned short xbh[64 * 64];   // swizzled [p][d]
    __shared__ __align__(16) unsigned short xbl[64 * 64];
    __shared__ float enh_lds[1024];                         // 4KB bias table
    __shared__ float mv1[64 * 2], mv2[64 * 2];
    __shared__ int mi1[64 * 2];
    __shared__ int ks[64];
    __shared__ float red[4];
    __shared__ float xp[64];
    __shared__ int rl[64];
    __shared__ int rn;
    __shared__ float rv[4];
    __shared__ int ri[4];
    // LDS ~= 71KB -> 2 blocks/CU (grid 512 = 2/CU exactly)

    const int tid = threadIdx.x;
    const int wave = tid >> 6, lane = tid & 63;
    const int n0 = (blockIdx.x + 512) * 64;   // second half of the points
    const int b = n0 >> 12;
    const int hw0 = n0 & 4095;

    const char* ehTb = (const char*)ehT;
    const char* elTb = (const char*)elT;
    const int lofs = wave * 1024 + lane * 16;

    // DMA(0) into buf0 (oldest vmcnt ops; x-prep consumption may drain them early)
    {
        char* db = ebuf;
        gld_lds16(ehTb + lofs,        db + wave * 1024);
        gld_lds16(ehTb + 4096 + lofs, db + 4096 + wave * 1024);
        gld_lds16(elTb + lofs,        db + 8192 + wave * 1024);
        gld_lds16(elTb + 4096 + lofs, db + 12288 + wave * 1024);
    }
    if (tid == 0) rn = 0;
    // enh -> LDS (removes ALL in-loop global loads)
    *(float4*)(enh_lds + tid * 4) = *(const float4*)(enh + tid * 4);

    // x prep identical to A, staged in buf1's 16KB
    float* xsc = (float*)(ebuf + 16384);
    {
        const int d = tid >> 2, ph = tid & 3;
        const float* src = x + ((b * DD + d) << 12) + hw0 + ph * 16;
        float* dst = xsc + d * 64 + ph * 16;
#pragma unroll
        for (int j = 0; j < 4; ++j)
            *(float4*)(dst + j * 4) = *(const float4*)(src + j * 4);
    }
    __syncthreads();
    {
        const int p = tid >> 2, dq = tid & 3;
#pragma unroll
        for (int s = 0; s < 16; ++s) {
            const int d = dq * 16 + s;
            const float f = xsc[d * 64 + p];
            const unsigned short h = bf16_rne(f);
            const int pos = p * 64 + swz(p, d);
            xbh[pos] = h;
            xbl[pos] = bf16_rne(f - bf16_to_f(h));
        }
    }
    __syncthreads();   // xsc reads done for ALL waves -> buf1 free for DMA(1)

    // DMA(1) into buf1
    {
        char* db = ebuf + 16384;
        const char* sH = ehTb + 8192 + lofs;
        const char* sL = elTb + 8192 + lofs;
        gld_lds16(sH,        db + wave * 1024);
        gld_lds16(sH + 4096, db + 4096 + wave * 1024);
        gld_lds16(sL,        db + 8192 + wave * 1024);
        gld_lds16(sL + 4096, db + 12288 + wave * 1024);
    }

    const int ln15 = lane & 15, q8 = (lane >> 4) * 8;
    const int wp = (wave >> 1) * 32;
    const int wc = (wave & 1) * 32;

    short8 ah[2][2], al[2][2];
#pragma unroll
    for (int rf = 0; rf < 2; ++rf)
#pragma unroll
        for (int kc = 0; kc < 2; ++kc) {
            const int pp = wp + rf * 16 + ln15;
            const int pos = pp * 64 + ((kc * 32 + q8) ^ ((pp & 7) << 3));
            ah[rf][kc] = *(const short8*)(xbh + pos);
            al[rf][kc] = *(const short8*)(xbl + pos);
        }

    unsigned v1u[8], v2u[8];
#pragma unroll
    for (int r = 0; r < 8; ++r) { v1u[r] = 0u; v2u[r] = 0u; }

    // Pipelined loop. Outstanding-DMA ledger (per wave, 8 ops per tile):
    //   kt=0 wait: {DMA0,DMA1}=16 -> vmcnt(8) completes DMA0. issue DMA2.
    //   kt=1 wait: {DMA1,DMA2}=16 -> vmcnt(8) completes DMA1. issue DMA3.
    //   ... steady: vmcnt(8) completes DMA(kt); issue DMA(kt+2) while kt<14.
    //   kt=14 wait: {DMA14,DMA15}=16 -> vmcnt(8) completes DMA14. no issue.
    //   kt=15 wait: {DMA15}=8 -> vmcnt(0) completes DMA15.
    for (int kt = 0; kt < 16; ++kt) {
        if (kt < 15) asm volatile("s_waitcnt vmcnt(8)" ::: "memory");
        else         asm volatile("s_waitcnt vmcnt(0)" ::: "memory");
        __builtin_amdgcn_s_barrier();   // all waves' DMA(kt) landed; buf[(kt-1)%3] readers done
        if (kt < 14) {
            const int nkt = kt + 2;
            char* db = ebuf + (nkt % 3) * 16384;
            const char* sH = ehTb + nkt * 8192 + lofs;
            const char* sL = elTb + nkt * 8192 + lofs;
            gld_lds16(sH,        db + wave * 1024);
            gld_lds16(sH + 4096, db + 4096 + wave * 1024);
            gld_lds16(sL,        db + 8192 + wave * 1024);
            gld_lds16(sL + 4096, db + 12288 + wave * 1024);
        }
        const unsigned short* ebH = (const unsigned short*)(ebuf + (kt % 3) * 16384);
        const unsigned short* ebL = ebH + 4096;

        f32x4 acc[2][2];
#pragma unroll
        for (int cf = 0; cf < 2; ++cf) {
            const float ec = enh_lds[kt * 64 + wc + cf * 16 + ln15];
#pragma unroll
            for (int rf = 0; rf < 2; ++rf)
                acc[rf][cf] = (f32x4){ec, ec, ec, ec};
        }

#pragma unroll
        for (int kc = 0; kc < 2; ++kc) {
            short8 bh[2], bl[2];
#pragma unroll
            for (int cf = 0; cf < 2; ++cf) {
                const int c = wc + cf * 16 + ln15;
                const int pos = c * 64 + ((kc * 32 + q8) ^ ((c & 7) << 3));
                bh[cf] = *(const short8*)(ebH + pos);
                bl[cf] = *(const short8*)(ebL + pos);
            }
#pragma unroll
            for (int rf = 0; rf < 2; ++rf)
#pragma unroll
                for (int cf = 0; cf < 2; ++cf) {
                    acc[rf][cf] = __builtin_amdgcn_mfma_f32_16x16x32_bf16(al[rf][kc], bh[cf], acc[rf][cf], 0, 0, 0);
                    acc[rf][cf] = __builtin_amdgcn_mfma_f32_16x16x32_bf16(ah[rf][kc], bl[cf], acc[rf][cf], 0, 0, 0);
                    acc[rf][cf] = __builtin_amdgcn_mfma_f32_16x16x32_bf16(ah[rf][kc], bh[cf], acc[rf][cf], 0, 0, 0);
                }
        }

#pragma unroll
        for (int rf = 0; rf < 2; ++rf)
#pragma unroll
            for (int reg = 0; reg < 4; ++reg) {
                const int r = rf * 4 + reg;
                const unsigned k0 = (__float_as_uint(acc[rf][0][reg]) | 31u) ^ (unsigned)(kt * 2 + 0);
                const unsigned k1 = (__float_as_uint(acc[rf][1][reg]) | 31u) ^ (unsigned)(kt * 2 + 1);
                const unsigned a = umax(k0, k1), bb = umin(k0, k1);
                v2u[r] = umax(umax(v2u[r], umin(v1u[r], a)), bb);
                v1u[r] = umax(v1u[r], a);
            }
    }
    __syncthreads();   // all waves done with tile 15

#pragma unroll
    for (int r = 0; r < 8; ++r) {
        const unsigned c5 = 31u - (v1u[r] & 31u);
        int col = (int)(c5 >> 1) * 64 + wc + (int)(c5 & 1) * 16 + ln15;
        float val = __uint_as_float(v1u[r] & ~31u);
        float sec = __uint_as_float(v2u[r] & ~31u);
#pragma unroll
        for (int msk = 1; msk < 16; msk <<= 1) {
            const float ov = __shfl_xor(val, msk);
            const int oc = __shfl_xor(col, msk);
            const float os = __shfl_xor(sec, msk);
            sec = fmaxf(fmaxf(sec, os), fminf(val, ov));
            const bool t = (ov > val) || (ov == val && oc < col);
            val = t ? ov : val;
            col = t ? oc : col;
        }
        if (ln15 == 0) {
            const int q = lane >> 4;
            const int h = wave & 1;
            const int pt = wp + (r >> 2) * 16 + q * 4 + (r & 3);
            mv1[pt * 2 + h] = val;
            mi1[pt * 2 + h] = col;
            mv2[pt * 2 + h] = sec;
        }
    }
    __syncthreads();
    if (tid < 64) {
        const float va = mv1[tid * 2], vb = mv1[tid * 2 + 1];
        const int ia = mi1[tid * 2], ib = mi1[tid * 2 + 1];
        const bool t = (vb > va) || (vb == va && ib < ia);
        const float bv = t ? vb : va;
        const int bi = t ? ib : ia;
        const float sec = fmaxf(fmaxf(mv2[tid * 2], mv2[tid * 2 + 1]), fminf(va, vb));
        ks[tid] = bi;
        if (bv - sec < MARGIN_S) {
            const int w = atomicAdd(&rn, 1);
            rl[w] = tid;
        }
    }
    __syncthreads();

    const int lcnt = rn;
    for (int it = 0; it < lcnt; ++it) {
        const int pr = rl[it];
        if (tid < 64) xp[tid] = x[((b * DD + tid) << 12) + hw0 + pr];
        __syncthreads();
        float d0 = 0.f, d1 = 0.f, d2 = 0.f, d3 = 0.f;
#pragma unroll 8
        for (int dd = 0; dd < DD; ++dd) {
            const float xd = xp[dd];
            const float4 ev = *(const float4*)(e + dd * KK + tid * 4);
            d0 = fmaf(xd, ev.x, d0);
            d1 = fmaf(xd, ev.y, d1);
            d2 = fmaf(xd, ev.z, d2);
            d3 = fmaf(xd, ev.w, d3);
        }
        const float4 ea = *(const float4*)(enh + tid * 4);
        float bs = d0 + ea.x;
        int bi2 = tid * 4;
        if (d1 + ea.y > bs) { bs = d1 + ea.y; bi2 = tid * 4 + 1; }
        if (d2 + ea.z > bs) { bs = d2 + ea.z; bi2 = tid * 4 + 2; }
        if (d3 + ea.w > bs) { bs = d3 + ea.w; bi2 = tid * 4 + 3; }
#pragma unroll
        for (int m = 1; m < 64; m <<= 1) {
            const float ov = __shfl_xor(bs, m, 64);
            const int oi = __shfl_xor(bi2, m, 64);
            if (ov > bs || (ov == bs && oi < bi2)) { bs = ov; bi2 = oi; }
        }
        if (lane == 0) { rv[wave] = bs; ri[wave] = bi2; }
        __syncthreads();
        if (tid == 0) {
            float gs = rv[0];
            int gi = ri[0];
#pragma unroll
            for (int t2 = 1; t2 < 4; ++t2)
                if (rv[t2] > gs || (rv[t2] == gs && ri[t2] < gi)) { gs = rv[t2]; gi = ri[t2]; }
            ks[pr] = gi;
        }
        __syncthreads();
    }

    if (tid < 64) out[OFF_IDX + n0 + tid] = (float)ks[tid];

    const int p = tid & 63, dqr = tid >> 6;
    const int kp = ks[p];
    float lacc = 0.f;
#pragma unroll
    for (int s = 0; s < 16; ++s) {
        const int d = dqr * 16 + s;
        const float qv = e[d * KK + kp];
        const float xv = x[((b * DD + d) << 12) + hw0 + p];
        out[((b * DD + d) << 12) + hw0 + p] = qv;
        const float df = xv - qv;
        lacc = fmaf(df, df, lacc);
    }
#pragma unroll
    for (int off = 32; off > 0; off >>= 1) lacc += __shfl_down(lacc, off, 64);
    if (lane == 0) red[wave] = lacc;
    __syncthreads();
    if (tid == 0) {
        atomicAdd(sum, red[0] + red[1] + red[2] + red[3]);
        __threadfence();
        const unsigned old = atomicAdd(tick, 1u);
        if (old == (unsigned)(NBLK_TOTAL - 1)) {
            const float s = atomicAdd(sum, 0.0f);
            const float m = s * (1.0f / (float)TOTAL);
            out[OFF_L1] = m;
            out[OFF_L2] = m;
        }
    }
}

extern "C" void kernel_launch(void* const* d_in, const int* in_sizes, int n_in,
                              void* d_out, int out_size, void* d_ws, size_t ws_size,
                              hipStream_t stream) {
    const float* x = (const float*)d_in[0];      // [16,64,64,64]
    const float* e = (const float*)d_in[1];      // [64,1024]
    float* out = (float*)d_out;

    float* sum = (float*)d_ws;
    unsigned* tick = (unsigned*)d_ws + 2;
    float* enh = (float*)d_ws + WS_ENH_F;
    unsigned short* ehT = (unsigned short*)((char*)d_ws + WS_EHT_BYTE);
    unsigned short* elT = (unsigned short*)((char*)d_ws + WS_ELT_BYTE);

    prep_kernel<<<KK / 64, 256, 0, stream>>>(e, enh, ehT, elT, sum, tick);
    vq_gemm_a<<<512, 256, 0, stream>>>(x, e, enh, ehT, elT, out, sum, tick);
    vq_gemm_b<<<512, 256, 0, stream>>>(x, e, enh, ehT, elT, out, sum, tick);
}

// Round 9
// 150.270 us; speedup vs baseline: 1.0605x; 1.0605x over previous
//
#include <hip/hip_runtime.h>

// VectorQuantizer: B=16, D=64, H=64, W=64, K=1024
#define DD 64
#define KK 1024
#define NPTS 65536
#define TOTAL 4194304
#define NBLK_TOTAL 1024   // ticket target (full gemm grid)

// Output layout (flat f32): quantized[4194304], L1, L2, idx[65536]
#define OFF_L1 4194304
#define OFF_L2 4194305
#define OFF_IDX 4194306

// ws layout (bytes): [0] f32 sum, [8] u32 ticket, enh @ float 64 (byte 256),
// ehT @ byte 65536 (128KB), elT @ byte 196608 (128KB). (<=328KB used)
#define WS_ENH_F 64
#define WS_EHT_BYTE 65536
#define WS_ELT_BYTE (65536 + 131072)

// score = dot(x,e) + 512 - ||e||^2/2  (argmax == argmin distance; +512 keeps
// all scores positive so float bits are monotone -> packed uint compare).
// Rescue margin: 32-ulp granule (<=2e-3) + bf16x3 err (~6e-4) + slack.
#define MARGIN_S 0.006f

typedef __attribute__((ext_vector_type(8))) short short8;
typedef __attribute__((ext_vector_type(4))) float f32x4;

__device__ __forceinline__ unsigned short bf16_rne(float f) {
    unsigned b = __float_as_uint(f);
    return (unsigned short)((b + 0x7FFFu + ((b >> 16) & 1u)) >> 16);
}
__device__ __forceinline__ float bf16_to_f(unsigned short h) {
    return __uint_as_float(((unsigned)h) << 16);
}
__device__ __forceinline__ unsigned umax(unsigned a, unsigned b) { return a > b ? a : b; }
__device__ __forceinline__ unsigned umin(unsigned a, unsigned b) { return a < b ? a : b; }
// async global->LDS DMA, 16B per lane; LDS dest = wave-uniform base + lane*16
__device__ __forceinline__ void gld_lds16(const void* g, void* l) {
    __builtin_amdgcn_global_load_lds(
        (const __attribute__((address_space(1))) void*)g,
        (__attribute__((address_space(3))) void*)l, 16, 0, 0);
}
// swizzled position of element d within a 64-elem row r (16B-granule XOR key)
__device__ __forceinline__ int swz(int r, int d) {
    return ((d & ~7) ^ ((r & 7) << 3)) | (d & 7);
}

// ---------- kernel 1: enh + swizzled bf16 hi/lo codebook [k][64] ----------
__global__ __launch_bounds__(256) void prep_kernel(const float* __restrict__ e,
                                                   float* __restrict__ enh,
                                                   unsigned short* __restrict__ ehT,
                                                   unsigned short* __restrict__ elT,
                                                   float* __restrict__ sum,
                                                   unsigned* __restrict__ tick) {
    __shared__ unsigned short tH[64 * 64];   // 8KB [code_local][swz d]
    __shared__ unsigned short tL[64 * 64];
    __shared__ float ps[4 * 64];
    const int tid = threadIdx.x, wave = tid >> 6, lane = tid & 63;
    if (blockIdx.x == 0 && tid == 0) { *sum = 0.f; *tick = 0u; }
    const int k = blockIdx.x * 64 + lane;    // this thread's code
    float s2 = 0.f;
    short8 hh[2], ll[2];
#pragma unroll
    for (int g = 0; g < 2; ++g)
#pragma unroll
        for (int j = 0; j < 8; ++j) {
            const int d = wave * 16 + g * 8 + j;
            const float v = e[d * KK + k];   // lanes k-contiguous -> 256B coalesced
            const unsigned short h = bf16_rne(v);
            hh[g][j] = (short)h;
            ll[g][j] = (short)bf16_rne(v - bf16_to_f(h));
            s2 = fmaf(v, v, s2);
        }
    ps[wave * 64 + lane] = s2;
#pragma unroll
    for (int g = 0; g < 2; ++g) {
        const int pos = lane * 64 + ((wave * 16 + g * 8) ^ ((k & 7) << 3));
        *(short8*)(tH + pos) = hh[g];
        *(short8*)(tL + pos) = ll[g];
    }
    __syncthreads();
    if (wave == 0) {
        const float t = ps[lane] + ps[64 + lane] + ps[128 + lane] + ps[192 + lane];
        enh[k] = 512.0f - 0.5f * t;
    }
    {
        const short8* srcH = (const short8*)tH;
        const short8* srcL = (const short8*)tL;
        short8* dstH = (short8*)(ehT + blockIdx.x * 64 * 64);
        short8* dstL = (short8*)(elT + blockIdx.x * 64 * 64);
        dstH[tid * 2]     = srcH[tid * 2];
        dstH[tid * 2 + 1] = srcH[tid * 2 + 1];
        dstL[tid * 2]     = srcL[tid * 2];
        dstL[tid * 2 + 1] = srcL[tid * 2 + 1];
    }
}

// ---------- kernel 2: counted-vmcnt triple-buffer (the r8 A/B WINNER),
//            now at full grid ----------
// r8 within-run A/B (same container, back-to-back): A = r0 2-buf
// __syncthreads body, 49.8us/512 blocks; B = THIS body, absent from top-5
// -> <49.4us/512. Cross-container variance is ~1.5x (r7: identical code
// 58.5 vs 87us), so only this within-run comparison is trusted.
// Structure: 3x16KB tile buffers, DMA(kt+2) issued right after barrier(kt)
// into buf[(kt-1)%3] (readers finished before barrier(kt)); counted
// s_waitcnt vmcnt(8) -- NEVER 0 mid-loop -- + raw s_barrier; NO
// sched_barrier (r3/m141 anti-pattern); enh in LDS so the loop has zero
// other vmcnt ops. Outstanding-DMA ledger (8 ops/tile/wave):
//   kt=0 wait: <= {DMA0,DMA1}=16 outstanding -> vmcnt(8) completes DMA0.
//   steady kt: {DMA(kt),DMA(kt+1)}=16 -> vmcnt(8) completes DMA(kt);
//              then issue DMA(kt+2) while kt<14.
//   kt=15: {DMA15}=8 -> vmcnt(0).
// Lessons kept: NO __launch_bounds__ min-waves (r1/r2: VGPR squeeze ->
// AGPR shuffles/spills).
__global__ __launch_bounds__(256) void vq_gemm(const float* __restrict__ x,
                                               const float* __restrict__ e,
                                               const float* __restrict__ enh,
                                               const unsigned short* __restrict__ ehT,
                                               const unsigned short* __restrict__ elT,
                                               float* __restrict__ out,
                                               float* __restrict__ sum,
                                               unsigned* __restrict__ tick) {
    __shared__ __align__(16) char ebuf[3 * 16384];          // 48KB triple buffer
    __shared__ __align__(16) unsigned short xbh[64 * 64];   // swizzled [p][d]
    __shared__ __align__(16) unsigned short xbl[64 * 64];
    __shared__ float enh_lds[1024];                         // 4KB bias table
    __shared__ float mv1[64 * 2], mv2[64 * 2];
    __shared__ int mi1[64 * 2];
    __shared__ int ks[64];
    __shared__ float red[4];
    __shared__ float xp[64];
    __shared__ int rl[64];
    __shared__ int rn;
    __shared__ float rv[4];
    __shared__ int ri[4];
    // LDS ~= 71KB -> 2 blocks/CU; 1024 blocks run as 2 residency waves.

    const int tid = threadIdx.x;
    const int wave = tid >> 6, lane = tid & 63;
    const int n0 = blockIdx.x * 64;
    const int b = n0 >> 12;
    const int hw0 = n0 & 4095;

    const char* ehTb = (const char*)ehT;
    const char* elTb = (const char*)elT;
    const int lofs = wave * 1024 + lane * 16;

    // DMA(0) into buf0
    {
        char* db = ebuf;
        gld_lds16(ehTb + lofs,        db + wave * 1024);
        gld_lds16(ehTb + 4096 + lofs, db + 4096 + wave * 1024);
        gld_lds16(elTb + lofs,        db + 8192 + wave * 1024);
        gld_lds16(elTb + 4096 + lofs, db + 12288 + wave * 1024);
    }
    if (tid == 0) rn = 0;
    // enh -> LDS (removes ALL in-loop global loads)
    *(float4*)(enh_lds + tid * 4) = *(const float4*)(enh + tid * 4);

    // x prep: fp32 stage into buf1's 16KB, then split-transpose to bf16 hi/lo
    float* xsc = (float*)(ebuf + 16384);
    {
        const int d = tid >> 2, ph = tid & 3;
        const float* src = x + ((b * DD + d) << 12) + hw0 + ph * 16;
        float* dst = xsc + d * 64 + ph * 16;
#pragma unroll
        for (int j = 0; j < 4; ++j)
            *(float4*)(dst + j * 4) = *(const float4*)(src + j * 4);
    }
    __syncthreads();
    {
        const int p = tid >> 2, dq = tid & 3;
#pragma unroll
        for (int s = 0; s < 16; ++s) {
            const int d = dq * 16 + s;
            const float f = xsc[d * 64 + p];
            const unsigned short h = bf16_rne(f);
            const int pos = p * 64 + swz(p, d);
            xbh[pos] = h;
            xbl[pos] = bf16_rne(f - bf16_to_f(h));
        }
    }
    __syncthreads();   // xsc reads done for ALL waves -> buf1 free for DMA(1)

    // DMA(1) into buf1
    {
        char* db = ebuf + 16384;
        const char* sH = ehTb + 8192 + lofs;
        const char* sL = elTb + 8192 + lofs;
        gld_lds16(sH,        db + wave * 1024);
        gld_lds16(sH + 4096, db + 4096 + wave * 1024);
        gld_lds16(sL,        db + 8192 + wave * 1024);
        gld_lds16(sL + 4096, db + 12288 + wave * 1024);
    }

    const int ln15 = lane & 15, q8 = (lane >> 4) * 8;
    const int wp = (wave >> 1) * 32;
    const int wc = (wave & 1) * 32;

    short8 ah[2][2], al[2][2];
#pragma unroll
    for (int rf = 0; rf < 2; ++rf)
#pragma unroll
        for (int kc = 0; kc < 2; ++kc) {
            const int pp = wp + rf * 16 + ln15;
            const int pos = pp * 64 + ((kc * 32 + q8) ^ ((pp & 7) << 3));
            ah[rf][kc] = *(const short8*)(xbh + pos);
            al[rf][kc] = *(const short8*)(xbl + pos);
        }

    unsigned v1u[8], v2u[8];
#pragma unroll
    for (int r = 0; r < 8; ++r) { v1u[r] = 0u; v2u[r] = 0u; }

    for (int kt = 0; kt < 16; ++kt) {
        if (kt < 15) asm volatile("s_waitcnt vmcnt(8)" ::: "memory");
        else         asm volatile("s_waitcnt vmcnt(0)" ::: "memory");
        __builtin_amdgcn_s_barrier();   // all waves' DMA(kt) landed; buf[(kt-1)%3] readers done
        if (kt < 14) {
            const int nkt = kt + 2;
            char* db = ebuf + (nkt % 3) * 16384;
            const char* sH = ehTb + nkt * 8192 + lofs;
            const char* sL = elTb + nkt * 8192 + lofs;
            gld_lds16(sH,        db + wave * 1024);
            gld_lds16(sH + 4096, db + 4096 + wave * 1024);
            gld_lds16(sL,        db + 8192 + wave * 1024);
            gld_lds16(sL + 4096, db + 12288 + wave * 1024);
        }
        const unsigned short* ebH = (const unsigned short*)(ebuf + (kt % 3) * 16384);
        const unsigned short* ebL = ebH + 4096;

        f32x4 acc[2][2];
#pragma unroll
        for (int cf = 0; cf < 2; ++cf) {
            const float ec = enh_lds[kt * 64 + wc + cf * 16 + ln15];
#pragma unroll
            for (int rf = 0; rf < 2; ++rf)
                acc[rf][cf] = (f32x4){ec, ec, ec, ec};
        }

#pragma unroll
        for (int kc = 0; kc < 2; ++kc) {
            short8 bh[2], bl[2];
#pragma unroll
            for (int cf = 0; cf < 2; ++cf) {
                const int c = wc + cf * 16 + ln15;
                const int pos = c * 64 + ((kc * 32 + q8) ^ ((c & 7) << 3));
                bh[cf] = *(const short8*)(ebH + pos);
                bl[cf] = *(const short8*)(ebL + pos);
            }
#pragma unroll
            for (int rf = 0; rf < 2; ++rf)
#pragma unroll
                for (int cf = 0; cf < 2; ++cf) {
                    acc[rf][cf] = __builtin_amdgcn_mfma_f32_16x16x32_bf16(al[rf][kc], bh[cf], acc[rf][cf], 0, 0, 0);
                    acc[rf][cf] = __builtin_amdgcn_mfma_f32_16x16x32_bf16(ah[rf][kc], bl[cf], acc[rf][cf], 0, 0, 0);
                    acc[rf][cf] = __builtin_amdgcn_mfma_f32_16x16x32_bf16(ah[rf][kc], bh[cf], acc[rf][cf], 0, 0, 0);
                }
        }

#pragma unroll
        for (int rf = 0; rf < 2; ++rf)
#pragma unroll
            for (int reg = 0; reg < 4; ++reg) {
                const int r = rf * 4 + reg;
                const unsigned k0 = (__float_as_uint(acc[rf][0][reg]) | 31u) ^ (unsigned)(kt * 2 + 0);
                const unsigned k1 = (__float_as_uint(acc[rf][1][reg]) | 31u) ^ (unsigned)(kt * 2 + 1);
                const unsigned a = umax(k0, k1), bb = umin(k0, k1);
                v2u[r] = umax(umax(v2u[r], umin(v1u[r], a)), bb);
                v1u[r] = umax(v1u[r], a);
            }
    }
    __syncthreads();   // all waves done with tile 15

#pragma unroll
    for (int r = 0; r < 8; ++r) {
        const unsigned c5 = 31u - (v1u[r] & 31u);
        int col = (int)(c5 >> 1) * 64 + wc + (int)(c5 & 1) * 16 + ln15;
        float val = __uint_as_float(v1u[r] & ~31u);
        float sec = __uint_as_float(v2u[r] & ~31u);
#pragma unroll
        for (int msk = 1; msk < 16; msk <<= 1) {
            const float ov = __shfl_xor(val, msk);
            const int oc = __shfl_xor(col, msk);
            const float os = __shfl_xor(sec, msk);
            sec = fmaxf(fmaxf(sec, os), fminf(val, ov));
            const bool t = (ov > val) || (ov == val && oc < col);
            val = t ? ov : val;
            col = t ? oc : col;
        }
        if (ln15 == 0) {
            const int q = lane >> 4;
            const int h = wave & 1;
            const int pt = wp + (r >> 2) * 16 + q * 4 + (r & 3);
            mv1[pt * 2 + h] = val;
            mi1[pt * 2 + h] = col;
            mv2[pt * 2 + h] = sec;
        }
    }
    __syncthreads();
    if (tid < 64) {
        const float va = mv1[tid * 2], vb = mv1[tid * 2 + 1];
        const int ia = mi1[tid * 2], ib = mi1[tid * 2 + 1];
        const bool t = (vb > va) || (vb == va && ib < ia);
        const float bv = t ? vb : va;
        const int bi = t ? ib : ia;
        const float sec = fmaxf(fmaxf(mv2[tid * 2], mv2[tid * 2 + 1]), fminf(va, vb));
        ks[tid] = bi;
        if (bv - sec < MARGIN_S) {
            const int w = atomicAdd(&rn, 1);
            rl[w] = tid;
        }
    }
    __syncthreads();

    // ---- in-block exact fp32 rescue (cold: ~0.16 items/block) ----
    const int lcnt = rn;
    for (int it = 0; it < lcnt; ++it) {
        const int pr = rl[it];
        if (tid < 64) xp[tid] = x[((b * DD + tid) << 12) + hw0 + pr];
        __syncthreads();
        float d0 = 0.f, d1 = 0.f, d2 = 0.f, d3 = 0.f;
#pragma unroll 8
        for (int dd = 0; dd < DD; ++dd) {
            const float xd = xp[dd];
            const float4 ev = *(const float4*)(e + dd * KK + tid * 4);
            d0 = fmaf(xd, ev.x, d0);
            d1 = fmaf(xd, ev.y, d1);
            d2 = fmaf(xd, ev.z, d2);
            d3 = fmaf(xd, ev.w, d3);
        }
        const float4 ea = *(const float4*)(enh + tid * 4);
        float bs = d0 + ea.x;
        int bi2 = tid * 4;
        if (d1 + ea.y > bs) { bs = d1 + ea.y; bi2 = tid * 4 + 1; }
        if (d2 + ea.z > bs) { bs = d2 + ea.z; bi2 = tid * 4 + 2; }
        if (d3 + ea.w > bs) { bs = d3 + ea.w; bi2 = tid * 4 + 3; }
#pragma unroll
        for (int m = 1; m < 64; m <<= 1) {
            const float ov = __shfl_xor(bs, m, 64);
            const int oi = __shfl_xor(bi2, m, 64);
            if (ov > bs || (ov == bs && oi < bi2)) { bs = ov; bi2 = oi; }
        }
        if (lane == 0) { rv[wave] = bs; ri[wave] = bi2; }
        __syncthreads();
        if (tid == 0) {
            float gs = rv[0];
            int gi = ri[0];
#pragma unroll
            for (int t2 = 1; t2 < 4; ++t2)
                if (rv[t2] > gs || (rv[t2] == gs && ri[t2] < gi)) { gs = rv[t2]; gi = ri[t2]; }
            ks[pr] = gi;
        }
        __syncthreads();
    }

    if (tid < 64) out[OFF_IDX + n0 + tid] = (float)ks[tid];

    // quantize + loss epilogue (exact fp32; x re-read coalesced from global)
    const int p = tid & 63, dqr = tid >> 6;
    const int kp = ks[p];
    float lacc = 0.f;
#pragma unroll
    for (int s = 0; s < 16; ++s) {
        const int d = dqr * 16 + s;
        const float qv = e[d * KK + kp];
        const float xv = x[((b * DD + d) << 12) + hw0 + p];
        out[((b * DD + d) << 12) + hw0 + p] = qv;
        const float df = xv - qv;
        lacc = fmaf(df, df, lacc);
    }
#pragma unroll
    for (int off = 32; off > 0; off >>= 1) lacc += __shfl_down(lacc, off, 64);
    if (lane == 0) red[wave] = lacc;
    __syncthreads();
    if (tid == 0) {
        atomicAdd(sum, red[0] + red[1] + red[2] + red[3]);
        __threadfence();
        const unsigned old = atomicAdd(tick, 1u);
        if (old == (unsigned)(NBLK_TOTAL - 1)) {
            const float s = atomicAdd(sum, 0.0f);
            const float m = s * (1.0f / (float)TOTAL);
            out[OFF_L1] = m;   // dictionary_loss
            out[OFF_L2] = m;   // commitment_loss (numerically identical)
        }
    }
}

extern "C" void kernel_launch(void* const* d_in, const int* in_sizes, int n_in,
                              void* d_out, int out_size, void* d_ws, size_t ws_size,
                              hipStream_t stream) {
    const float* x = (const float*)d_in[0];      // [16,64,64,64]
    const float* e = (const float*)d_in[1];      // [64,1024]
    float* out = (float*)d_out;

    float* sum = (float*)d_ws;
    unsigned* tick = (unsigned*)d_ws + 2;
    float* enh = (float*)d_ws + WS_ENH_F;
    unsigned short* ehT = (unsigned short*)((char*)d_ws + WS_EHT_BYTE);
    unsigned short* elT = (unsigned short*)((char*)d_ws + WS_ELT_BYTE);

    prep_kernel<<<KK / 64, 256, 0, stream>>>(e, enh, ehT, elT, sum, tick);
    vq_gemm<<<NPTS / 64, 256, 0, stream>>>(x, e, enh, ehT, elT, out, sum, tick);
}

// Round 10
// 125.549 us; speedup vs baseline: 1.2693x; 1.1969x over previous
//
#include <hip/hip_runtime.h>

// VectorQuantizer: B=16, D=64, H=64, W=64, K=1024
#define DD 64
#define KK 1024
#define NPTS 65536
#define TOTAL 4194304

// Output layout (flat f32): quantized[4194304], L1, L2, idx[65536]
#define OFF_L1 4194304
#define OFF_L2 4194305
#define OFF_IDX 4194306

// ws layout (bytes): [0] f32 sum, [8] u32 ticket, enh @ float 64 (byte 256),
// ehT @ byte 65536 (128KB), elT @ byte 196608 (128KB). (<=328KB used)
#define WS_ENH_F 64
#define WS_EHT_BYTE 65536
#define WS_ELT_BYTE (65536 + 131072)

// score = dot(x,e) + 512 - ||e||^2/2  (argmax == argmin distance; +512 keeps
// all scores positive so float bits are monotone -> packed uint compare).
// Rescue margin: 64-ulp granule (<=4.6e-3) + bf16x3 err (~6e-4) + slack.
#define MARGIN_S 0.008f

typedef __attribute__((ext_vector_type(8))) short short8;
typedef __attribute__((ext_vector_type(4))) float f32x4;

__device__ __forceinline__ unsigned short bf16_rne(float f) {
    unsigned b = __float_as_uint(f);
    return (unsigned short)((b + 0x7FFFu + ((b >> 16) & 1u)) >> 16);
}
__device__ __forceinline__ float bf16_to_f(unsigned short h) {
    return __uint_as_float(((unsigned)h) << 16);
}
__device__ __forceinline__ unsigned umax(unsigned a, unsigned b) { return a > b ? a : b; }
__device__ __forceinline__ unsigned umin(unsigned a, unsigned b) { return a < b ? a : b; }
// async global->LDS DMA, 16B per lane; LDS dest = wave-uniform base + lane*16
__device__ __forceinline__ void gld_lds16(const void* g, void* l) {
    __builtin_amdgcn_global_load_lds(
        (const __attribute__((address_space(1))) void*)g,
        (__attribute__((address_space(3))) void*)l, 16, 0, 0);
}
// swizzled position of element d within a 64-elem row r (16B-granule XOR key)
__device__ __forceinline__ int swz(int r, int d) {
    return ((d & ~7) ^ ((r & 7) << 3)) | (d & 7);
}

// ---------- kernel 1: enh + swizzled bf16 hi/lo codebook [k][64] ----------
__global__ __launch_bounds__(256) void prep_kernel(const float* __restrict__ e,
                                                   float* __restrict__ enh,
                                                   unsigned short* __restrict__ ehT,
                                                   unsigned short* __restrict__ elT,
                                                   float* __restrict__ sum,
                                                   unsigned* __restrict__ tick) {
    __shared__ unsigned short tH[64 * 64];   // 8KB [code_local][swz d]
    __shared__ unsigned short tL[64 * 64];
    __shared__ float ps[4 * 64];
    const int tid = threadIdx.x, wave = tid >> 6, lane = tid & 63;
    if (blockIdx.x == 0 && tid == 0) { *sum = 0.f; *tick = 0u; }
    const int k = blockIdx.x * 64 + lane;    // this thread's code
    float s2 = 0.f;
    short8 hh[2], ll[2];
#pragma unroll
    for (int g = 0; g < 2; ++g)
#pragma unroll
        for (int j = 0; j < 8; ++j) {
            const int d = wave * 16 + g * 8 + j;
            const float v = e[d * KK + k];   // lanes k-contiguous -> 256B coalesced
            const unsigned short h = bf16_rne(v);
            hh[g][j] = (short)h;
            ll[g][j] = (short)bf16_rne(v - bf16_to_f(h));
            s2 = fmaf(v, v, s2);
        }
    ps[wave * 64 + lane] = s2;
#pragma unroll
    for (int g = 0; g < 2; ++g) {
        const int pos = lane * 64 + ((wave * 16 + g * 8) ^ ((k & 7) << 3));
        *(short8*)(tH + pos) = hh[g];
        *(short8*)(tL + pos) = ll[g];
    }
    __syncthreads();
    if (wave == 0) {
        const float t = ps[lane] + ps[64 + lane] + ps[128 + lane] + ps[192 + lane];
        enh[k] = 512.0f - 0.5f * t;
    }
    {
        const short8* srcH = (const short8*)tH;
        const short8* srcL = (const short8*)tL;
        short8* dstH = (short8*)(ehT + blockIdx.x * 64 * 64);
        short8* dstL = (short8*)(elT + blockIdx.x * 64 * 64);
        dstH[tid * 2]     = srcH[tid * 2];
        dstH[tid * 2 + 1] = srcH[tid * 2 + 1];
        dstL[tid * 2]     = srcL[tid * 2];
        dstL[tid * 2 + 1] = srcL[tid * 2 + 1];
    }
}

// ---------- kernel 2: 128-pt blocks + 32KB LDS (the untested matrix corner:
//            HALF codebook traffic AND 4-blocks/CU residency headroom) ----------
// Residency series at full co-residency: 4/CU=77.7us (r4, full traffic),
// 3/CU=87 (r7), 2/CU=103 (r9). Traffic series: full@4/CU = half@2/CU = 77.7
// (r4 vs r5) -> both factors matter and cancelled when traded. This kernel
// takes both: grid 512 (traffic halved vs 64-pt) with LDS = ONLY the 32KB
// double buffer (x bf16 staged inside it pre-loop; frags then in regs,
// 32 VGPR/thr) -> ~4 blocks/CU capacity, whole grid co-resident with 2x
// headroom. Hot loop = A-structure (r8 within-run A/B: equal to counted
// vmcnt, and simpler). Exact-fp32 epilogue (absmax 3.9e-3 class). Lessons
// kept: NO __launch_bounds__ min-waves; NO hand vmcnt/sched_barrier.
__global__ __launch_bounds__(256) void vq_gemm(const float* __restrict__ x,
                                               const float* __restrict__ e,
                                               const float* __restrict__ enh,
                                               const unsigned short* __restrict__ ehT,
                                               const unsigned short* __restrict__ elT,
                                               float* __restrict__ out,
                                               float* __restrict__ sum,
                                               unsigned* __restrict__ tick) {
    __shared__ __align__(16) char ebuf[2 * 16384];   // the ONLY LDS (32KB)

    // prologue x-staging aliases (dead once frags are in regs)
    unsigned short* xbh = (unsigned short*)ebuf;            // 16KB [128 pt][64 d] hi
    unsigned short* xbl = (unsigned short*)(ebuf + 16384);  // 16KB lo
    // post-loop aliases into buf0 (= tile-14 region; its readers all passed
    // barrier(15), and each wave writes aliases only after its loop exit)
    int*   ks  = (int*)ebuf;            // [128] chosen code per point
    float* xp  = (float*)(ks + 128);    // [64]  rescue point (fp32)
    int*   rl  = (int*)(xp + 64);       // [128] ambiguous-point list
    int*   rn  = rl + 128;              // [1]
    float* rv  = (float*)(rn + 1);      // [4]
    int*   ri  = (int*)(rv + 4);        // [4]
    float* red = (float*)(ri + 4);      // [4]

    const int tid = threadIdx.x;
    const int wave = tid >> 6, lane = tid & 63;
    const int n0 = blockIdx.x * 128;
    const int b = n0 >> 12;
    const int hw0 = n0 & 4095;

    const char* ehTb = (const char*)ehT;
    const char* elTb = (const char*)elT;
    const int lofs = wave * 1024 + lane * 16;   // per-lane byte offset per pass

    // ---- x prep: coalesced global->reg, bf16 hi/lo pack into ebuf.
    // thread t: point p = t&127, d-half dg = t>>7 (32 d's each).
    {
        const int p = tid & 127, dg = tid >> 7;
        const float* xs = x + ((b * DD + dg * 32) << 12) + hw0 + p;
        float xv[32];
#pragma unroll
        for (int s = 0; s < 32; ++s) xv[s] = xs[s << 12];   // 512B coalesced rows
#pragma unroll
        for (int g = 0; g < 4; ++g) {
            short8 hh, ll;
#pragma unroll
            for (int j = 0; j < 8; ++j) {
                const float f = xv[g * 8 + j];
                const unsigned short h = bf16_rne(f);
                hh[j] = (short)h;
                ll[j] = (short)bf16_rne(f - bf16_to_f(h));
            }
            const int d0 = dg * 32 + g * 8;
            const int pos = p * 64 + (d0 ^ ((p & 7) << 3));
            *(short8*)(xbh + pos) = hh;
            *(short8*)(xbl + pos) = ll;
        }
    }
    __syncthreads();   // x-bf16 visible to all waves

    const int ln15 = lane & 15, q8 = (lane >> 4) * 8;
    const int wp = wave * 32;          // this wave's 32 points (ALL codes)

    short8 ah[2][2], al[2][2];         // persistent A frags [rf][kc] (32 VGPR)
#pragma unroll
    for (int rf = 0; rf < 2; ++rf)
#pragma unroll
        for (int kc = 0; kc < 2; ++kc) {
            const int pp = wp + rf * 16 + ln15;
            const int pos = pp * 64 + ((kc * 32 + q8) ^ ((pp & 7) << 3));
            ah[rf][kc] = *(const short8*)(xbh + pos);
            al[rf][kc] = *(const short8*)(xbl + pos);
        }
    __syncthreads();   // frags in regs everywhere; ebuf free for tile DMA

    // DMA(0) into buf0 (lone exposed DMA; the 16-tile loop hides the rest)
    {
        char* db = ebuf;
        gld_lds16(ehTb + lofs,        db + wave * 1024);
        gld_lds16(ehTb + 4096 + lofs, db + 4096 + wave * 1024);
        gld_lds16(elTb + lofs,        db + 8192 + wave * 1024);
        gld_lds16(elTb + 4096 + lofs, db + 12288 + wave * 1024);
    }

    unsigned v1u[8], v2u[8];
#pragma unroll
    for (int r = 0; r < 8; ++r) { v1u[r] = 0u; v2u[r] = 0u; }

    for (int kt = 0; kt < 16; ++kt) {
        __syncthreads();   // drains tile-kt DMA + all waves done with kt-1
        if (kt < 15) {     // stream tile kt+1 into the other buffer
            const int nkt = kt + 1;
            char* db = ebuf + (nkt & 1) * 16384;
            const char* sH = ehTb + nkt * 8192 + lofs;
            const char* sL = elTb + nkt * 8192 + lofs;
            gld_lds16(sH,        db + wave * 1024);
            gld_lds16(sH + 4096, db + 4096 + wave * 1024);
            gld_lds16(sL,        db + 8192 + wave * 1024);
            gld_lds16(sL + 4096, db + 12288 + wave * 1024);
        }
        const unsigned short* ebH = (const unsigned short*)(ebuf + (kt & 1) * 16384);
        const unsigned short* ebL = ebH + 4096;

        // acc init = 512 - ||e||^2/2 (biased argmax score)
        f32x4 acc[2][4];
#pragma unroll
        for (int cf = 0; cf < 4; ++cf) {
            const float ec = enh[kt * 64 + cf * 16 + ln15];
#pragma unroll
            for (int rf = 0; rf < 2; ++rf)
                acc[rf][cf] = (f32x4){ec, ec, ec, ec};
        }

#pragma unroll
        for (int kc = 0; kc < 2; ++kc) {
            short8 bh[4], bl[4];
#pragma unroll
            for (int cf = 0; cf < 4; ++cf) {
                const int c = cf * 16 + ln15;
                const int pos = c * 64 + ((kc * 32 + q8) ^ ((c & 7) << 3));
                bh[cf] = *(const short8*)(ebH + pos);
                bl[cf] = *(const short8*)(ebL + pos);
            }
#pragma unroll
            for (int rf = 0; rf < 2; ++rf)
#pragma unroll
                for (int cf = 0; cf < 4; ++cf) {
                    acc[rf][cf] = __builtin_amdgcn_mfma_f32_16x16x32_bf16(al[rf][kc], bh[cf], acc[rf][cf], 0, 0, 0);
                    acc[rf][cf] = __builtin_amdgcn_mfma_f32_16x16x32_bf16(ah[rf][kc], bl[cf], acc[rf][cf], 0, 0, 0);
                    acc[rf][cf] = __builtin_amdgcn_mfma_f32_16x16x32_bf16(ah[rf][kc], bh[cf], acc[rf][cf], 0, 0, 0);
                }
        }

        // packed-key top-2 per (rf,reg) row: key = (bits|63) ^ (kt*4+cf)
        // (low6 = 63^col6 -> umax tie-breaks toward SMALLER col6 = smaller k)
#pragma unroll
        for (int rf = 0; rf < 2; ++rf)
#pragma unroll
            for (int reg = 0; reg < 4; ++reg) {
                const int r = rf * 4 + reg;
                const unsigned k0 = (__float_as_uint(acc[rf][0][reg]) | 63u) ^ (unsigned)(kt * 4 + 0);
                const unsigned k1 = (__float_as_uint(acc[rf][1][reg]) | 63u) ^ (unsigned)(kt * 4 + 1);
                const unsigned k2 = (__float_as_uint(acc[rf][2][reg]) | 63u) ^ (unsigned)(kt * 4 + 2);
                const unsigned k3 = (__float_as_uint(acc[rf][3][reg]) | 63u) ^ (unsigned)(kt * 4 + 3);
                unsigned a = umax(k0, k1), bb = umin(k0, k1);
                v2u[r] = umax(umax(v2u[r], umin(v1u[r], a)), bb);
                v1u[r] = umax(v1u[r], a);
                a = umax(k2, k3); bb = umin(k2, k3);
                v2u[r] = umax(umax(v2u[r], umin(v1u[r], a)), bb);
                v1u[r] = umax(v1u[r], a);
            }
    }

    __syncthreads();   // all waves done with tile 15 -> ebuf aliases safe
    if (tid == 0) *rn = 0;
    __syncthreads();

    // decode + cross-lane merge within the 16 lanes sharing each row-set.
    // Each wave covers ALL codes for its 32 pts -> result is final per point.
#pragma unroll
    for (int r = 0; r < 8; ++r) {
        const unsigned c6 = 63u - (v1u[r] & 63u);
        int col = (int)(c6 >> 2) * 64 + (int)(c6 & 3) * 16 + ln15;
        float val = __uint_as_float(v1u[r] & ~63u);
        float sec = __uint_as_float(v2u[r] & ~63u);
#pragma unroll
        for (int msk = 1; msk < 16; msk <<= 1) {
            const float ov = __shfl_xor(val, msk);
            const int oc = __shfl_xor(col, msk);
            const float os = __shfl_xor(sec, msk);
            sec = fmaxf(fmaxf(sec, os), fminf(val, ov));
            const bool t = (ov > val) || (ov == val && oc < col);
            val = t ? ov : val;
            col = t ? oc : col;
        }
        if (ln15 == 0) {
            const int qq = lane >> 4;
            const int pt = wp + (r >> 2) * 16 + qq * 4 + (r & 3);
            ks[pt] = col;
            if (val - sec < MARGIN_S) {   // ambiguous under granule+bf16x3 bound
                const int w = atomicAdd(rn, 1);
                rl[w] = pt;               // <=128 entries possible
            }
        }
    }
    __syncthreads();

    // ---- in-block exact fp32 rescue (cold: ~0.3 items/block) ----
    const int lcnt = *rn;
    for (int it = 0; it < lcnt; ++it) {
        const int pr = rl[it];
        if (tid < 64) xp[tid] = x[((b * DD + tid) << 12) + hw0 + pr];
        __syncthreads();
        float d0 = 0.f, d1 = 0.f, d2 = 0.f, d3 = 0.f;
#pragma unroll 8
        for (int dd = 0; dd < DD; ++dd) {
            const float xd = xp[dd];
            const float4 ev = *(const float4*)(e + dd * KK + tid * 4);
            d0 = fmaf(xd, ev.x, d0);
            d1 = fmaf(xd, ev.y, d1);
            d2 = fmaf(xd, ev.z, d2);
            d3 = fmaf(xd, ev.w, d3);
        }
        const float4 ea = *(const float4*)(enh + tid * 4);
        float bs = d0 + ea.x;
        int bi2 = tid * 4;
        if (d1 + ea.y > bs) { bs = d1 + ea.y; bi2 = tid * 4 + 1; }
        if (d2 + ea.z > bs) { bs = d2 + ea.z; bi2 = tid * 4 + 2; }
        if (d3 + ea.w > bs) { bs = d3 + ea.w; bi2 = tid * 4 + 3; }
#pragma unroll
        for (int m = 1; m < 64; m <<= 1) {
            const float ov = __shfl_xor(bs, m, 64);
            const int oi = __shfl_xor(bi2, m, 64);
            if (ov > bs || (ov == bs && oi < bi2)) { bs = ov; bi2 = oi; }
        }
        if (lane == 0) { rv[wave] = bs; ri[wave] = bi2; }
        __syncthreads();
        if (tid == 0) {
            float gs = rv[0];
            int gi = ri[0];
#pragma unroll
            for (int t2 = 1; t2 < 4; ++t2)
                if (rv[t2] > gs || (rv[t2] == gs && ri[t2] < gi)) { gs = rv[t2]; gi = ri[t2]; }
            ks[pr] = gi;
        }
        __syncthreads();
    }

    if (tid < 128) out[OFF_IDX + n0 + tid] = (float)ks[tid];

    // ---- quantize + loss epilogue (exact fp32; x re-read, e gathered) ----
    {
        const int pe = tid & 127, dh = tid >> 7;   // 32 d's per thread
        const int kp = ks[pe];
        float lacc = 0.f;
#pragma unroll
        for (int s = 0; s < 32; ++s) {
            const int d = dh * 32 + s;
            const float qv = e[d * KK + kp];
            const float xv = x[((b * DD + d) << 12) + hw0 + pe];
            out[((b * DD + d) << 12) + hw0 + pe] = qv;
            const float df = xv - qv;
            lacc = fmaf(df, df, lacc);
        }
#pragma unroll
        for (int off = 32; off > 0; off >>= 1) lacc += __shfl_down(lacc, off, 64);
        if (lane == 0) red[wave] = lacc;
    }
    __syncthreads();
    if (tid == 0) {
        atomicAdd(sum, red[0] + red[1] + red[2] + red[3]);
        __threadfence();
        const unsigned old = atomicAdd(tick, 1u);
        if (old == (unsigned)(gridDim.x - 1)) {
            const float s = atomicAdd(sum, 0.0f);
            const float m = s * (1.0f / (float)TOTAL);
            out[OFF_L1] = m;   // dictionary_loss
            out[OFF_L2] = m;   // commitment_loss (numerically identical)
        }
    }
}

extern "C" void kernel_launch(void* const* d_in, const int* in_sizes, int n_in,
                              void* d_out, int out_size, void* d_ws, size_t ws_size,
                              hipStream_t stream) {
    const float* x = (const float*)d_in[0];      // [16,64,64,64]
    const float* e = (const float*)d_in[1];      // [64,1024]
    float* out = (float*)d_out;

    float* sum = (float*)d_ws;
    unsigned* tick = (unsigned*)d_ws + 2;
    float* enh = (float*)d_ws + WS_ENH_F;
    unsigned short* ehT = (unsigned short*)((char*)d_ws + WS_EHT_BYTE);
    unsigned short* elT = (unsigned short*)((char*)d_ws + WS_ELT_BYTE);

    prep_kernel<<<KK / 64, 256, 0, stream>>>(e, enh, ehT, elT, sum, tick);
    vq_gemm<<<NPTS / 128, 256, 0, stream>>>(x, e, enh, ehT, elT, out, sum, tick);
}